// Round 4
// baseline (265.335 us; speedup 1.0000x reference)
//
#include <hip/hip_runtime.h>

// ComHG graph attention: N=50000, E=1.6M, DIN=128, DOUT=256, DA=32
// Round 10 (node occupancy):
//  - node: 256 -> 512 threads (8 waves/block). Grid stays 782 (one 64-node
//    bucket per block): 3.05 blocks/CU x 8 waves = ~24 waves/CU resident
//    (was 12) -> 2x memory-level parallelism for the random-gather phase,
//    which R9 counters showed to be latency-bound (5.6 outstanding
//    lines/CU vs 600cyc latency; 2.9 TB/s at only 26% occupancy).
//  - node: 64-entry hist scan via single-wave __shfl_up (12 barriers -> 1).
//  - everything else unchanged (controls).
// Pipeline (5 dispatches):
//   K0 wconv: Wxt(bf16 [n][k]); wrct(bf16 [64][128]); bcursor[b]=b*BCAP
//   K1 proj:  MFMA: a_row(f32)=x@W_row*rsqrt(DA); a_colh=bf16(x@W_col);
//             xh=bf16(x)
//   K2 part:  per 8192-edge block: LDS hist -> reserve sub-ranges in padded
//             bcursor -> write ibuf{rowlocal<<16|col, adj} contiguous runs
//   K3 node:  per-bucket LDS sort + fused logits/softmax/SpMM -> feath(bf16)
//   K4 gemm:  out = feath @ Wxt^T + b_x   (MFMA bf16, f32 acc)
// (global-max shift dropped: cancels in p/deg up to 1e-15 eps)

#define DIN   128
#define DOUT  256
#define DA    32
#define SLOPE 0.2f
#define RSQRT_DA 0.17677669529663687f   // 1/sqrt(32)
#define BSH   6                         // 64 nodes per bucket
#define BCAP  2560                      // bucket capacity: mean 2048, +11sigma
#define CSTRIDE 32                      // bcursor padding: 1 counter / 128B
#define NBMAX 800                       // LDS sizing; nb = ceil(n/64) = 782
#define PB_CHUNK 8192

typedef unsigned int uint;
typedef unsigned short ushort;
typedef __attribute__((ext_vector_type(8))) short bf16x8;
typedef __attribute__((ext_vector_type(4))) float f32x4;

static __device__ __forceinline__ ushort f2bf(float f) {
  const uint u = __float_as_uint(f);
  return (ushort)((u + 0x7fffu + ((u >> 16) & 1u)) >> 16);
}

// ---------------- K0: weight prep + bucket cursor init ----------------
// blocks 0..15 : Wx (f32 [k][n=256]) -> Wxt (bf16 [n][k])
// blocks 16..19: [Wr|Wc] (f32 [k][32] each) -> wrct (bf16 [c=64][k=128])
// block  20    : bcursor[b*CSTRIDE] = b*BCAP
__global__ __launch_bounds__(256) void wconv_kernel(
    const float* __restrict__ Wx, ushort* __restrict__ wxt,
    const float* __restrict__ Wr, const float* __restrict__ Wc,
    ushort* __restrict__ wrct, int* __restrict__ bcursor, int nb) {
  __shared__ ushort s[16][DIN];
  const int t = threadIdx.x;
  const int b = blockIdx.x;
  if (b < 16) {
    const int c0 = b * 16;
#pragma unroll
    for (int u = 0; u < 8; ++u) {
      const int k = u * 16 + (t >> 4);
      s[t & 15][k] = f2bf(Wx[(size_t)k * DOUT + c0 + (t & 15)]);
    }
    __syncthreads();
    const int c = t >> 4;          // 0..15
    const int kk = (t & 15) * 8;   // 0..120
    *(uint4*)(wxt + (size_t)(c0 + c) * DIN + kk) = *(const uint4*)&s[c][kk];
  } else if (b < 20) {
    const int c = (b - 16) * 16 + (t >> 4);   // 0..63
    const int k0 = (t & 15) * 8;              // 0..120
    const float* src = (c < DA) ? (Wr + c) : (Wc + (c - DA));
    ushort h[8];
#pragma unroll
    for (int j = 0; j < 8; ++j) h[j] = f2bf(src[(size_t)(k0 + j) * DA]);
    uint4 v;
    v.x = (uint)h[0] | ((uint)h[1] << 16);
    v.y = (uint)h[2] | ((uint)h[3] << 16);
    v.z = (uint)h[4] | ((uint)h[5] << 16);
    v.w = (uint)h[6] | ((uint)h[7] << 16);
    *(uint4*)(wrct + (size_t)c * DIN + k0) = v;
  } else {
    for (int i = t; i < nb; i += 256) bcursor[i * CSTRIDE] = i * BCAP;
  }
}

// ---------------- K1: MFMA projections + bf16 x copy ----------------
__global__ __launch_bounds__(256) void proj_kernel(
    const float* __restrict__ x, const ushort* __restrict__ wrct,
    float* __restrict__ a_row, ushort* __restrict__ a_colh,
    ushort* __restrict__ xh) {
  __shared__ ushort xb[16][136];   // +8 ushort pad: 2-way bank conflict only
  const int t = threadIdx.x;
  const int node0 = blockIdx.x * 16;
  const float4* xg = (const float4*)(x + (size_t)node0 * DIN);
#pragma unroll
  for (int u = 0; u < 2; ++u) {
    const int f = t + u * 256;               // 0..511 = node*32 + c4
    const float4 v = xg[f];
    ushort4 h;
    h.x = f2bf(v.x); h.y = f2bf(v.y); h.z = f2bf(v.z); h.w = f2bf(v.w);
    *(ushort4*)&xb[f >> 5][(f & 31) * 4] = h;
    ((ushort4*)(xh + (size_t)node0 * DIN))[f] = h;
  }
  __syncthreads();

  const int w = t >> 6;
  const int l = t & 63;
  const int lr = l & 15;
  const int lk = (l >> 4) * 8;
  f32x4 acc = {0.f, 0.f, 0.f, 0.f};
#pragma unroll
  for (int kk = 0; kk < 4; ++kk) {
    const bf16x8 a = *(const bf16x8*)&xb[lr][kk * 32 + lk];
    const bf16x8 bb =
        *(const bf16x8*)(wrct + (size_t)(w * 16 + lr) * DIN + kk * 32 + lk);
    acc = __builtin_amdgcn_mfma_f32_16x16x32_bf16(a, bb, acc, 0, 0, 0);
  }
  const int col = w * 16 + lr;     // 0..63 of [a_row | a_col]
  const int r0 = (l >> 4) * 4;
#pragma unroll
  for (int r = 0; r < 4; ++r) {
    const int node = node0 + r0 + r;
    if (col < DA)
      a_row[(size_t)node * DA + col] = acc[r] * RSQRT_DA;
    else
      a_colh[(size_t)node * DA + (col - DA)] = f2bf(acc[r]);
  }
}

// ---------------- K2: partition into buckets (fixed regions) ----------------
// Per-(block,bucket) contiguous sub-range reserved from padded cursors.
__global__ __launch_bounds__(512) void part_kernel(
    const int* __restrict__ row, const int* __restrict__ col,
    const float* __restrict__ adj, int* __restrict__ bcursor,
    int2* __restrict__ ibuf, int nb, int E) {
  __shared__ int hist[NBMAX];
  __shared__ int base[NBMAX];
  const int t = threadIdx.x;
  const int e0 = blockIdx.x * PB_CHUNK;
  for (int b = t; b < nb; b += 512) hist[b] = 0;
  __syncthreads();
  for (int u = 0; u < PB_CHUNK / 512; ++u) {
    const int e = e0 + u * 512 + t;
    if (e < E) atomicAdd(&hist[row[e] >> BSH], 1);
  }
  __syncthreads();
  for (int b = t; b < nb; b += 512) {
    const int c = hist[b];
    base[b] = c ? atomicAdd(&bcursor[b * CSTRIDE], c) : 0;
    hist[b] = 0;   // reuse as intra-block rank counter (same-thread, safe)
  }
  __syncthreads();
  for (int u = 0; u < PB_CHUNK / 512; ++u) {
    const int e = e0 + u * 512 + t;
    if (e < E) {
      const int r = row[e];
      const int b = r >> BSH;
      const int pos = base[b] + atomicAdd(&hist[b], 1);
      ibuf[pos] = make_int2(((r & 63) << 16) | col[e], __float_as_int(adj[e]));
    }
  }
}

// ---------------- K3: per-bucket sort + fused logits/softmax/SpMM ----------
// Block = one 64-node bucket, 512 thr (8 waves -> ~24 waves/CU resident).
// Stage bucket edges to regs, LDS hist + single-wave shfl scan + scatter ->
// sorted eL, then 2-nodes-per-wave pair loop (4 pairs per wave):
// wave = 2 nodes x 32 lanes, lane covers 4 feature cols via uint2 xh load.
#define NODE_BODY(J)                                                    \
  {                                                                     \
    const int2 e = spk[w][half][(J)];                                   \
    const float pv = sp[w][half][(J)];                                  \
    const uint2 xv = xh2[(size_t)e.x * 32 + la];                        \
    const float av = __int_as_float(e.y);                               \
    const float f0 = __uint_as_float(xv.x << 16);                       \
    const float f1 = __uint_as_float(xv.x & 0xffff0000u);               \
    const float f2 = __uint_as_float(xv.y << 16);                       \
    const float f3 = __uint_as_float(xv.y & 0xffff0000u);               \
    aa0 += av * f0; aa1 += av * f1; aa2 += av * f2; aa3 += av * f3;     \
    ap0 += pv * f0; ap1 += pv * f1; ap2 += pv * f2; ap3 += pv * f3;     \
    deg += pv;                                                          \
  }

__global__ __launch_bounds__(512) void node_kernel(
    const uint* __restrict__ xh, const float* __restrict__ a_row,
    const ushort* __restrict__ a_colh, const int* __restrict__ bcursor,
    const int2* __restrict__ ibuf, ushort* __restrict__ feath, int n) {
  __shared__ int2  eL[BCAP];          // 20 KB sorted {col, adj}
  __shared__ int   cnt[64];
  __shared__ int   excl[65];
  __shared__ int2  spk[8][2][32];
  __shared__ float sp[8][2][32];
  __shared__ float s_ar[8][2][32];
  const int t = threadIdx.x;
  const int b = blockIdx.x;
  const int node0 = b << BSH;
  const int estart = b * BCAP;
  const int ecnt = bcursor[b * CSTRIDE] - estart;

  if (t < 64) cnt[t] = 0;
  __syncthreads();
  int2 myv[BCAP / 512];
#pragma unroll
  for (int u = 0; u < BCAP / 512; ++u) {
    const int e = u * 512 + t;
    if (e < ecnt) {
      myv[u] = ibuf[estart + e];
      atomicAdd(&cnt[myv[u].x >> 16], 1);
    }
  }
  __syncthreads();
  if (t < 64) {                        // single-wave inclusive scan (shfl)
    const int v = cnt[t];
    int inc = v;
#pragma unroll
    for (int ofs = 1; ofs < 64; ofs <<= 1) {
      const int o = __shfl_up(inc, ofs, 64);
      if (t >= ofs) inc += o;
    }
    excl[t] = inc - v;                 // exclusive
    if (t == 63) excl[64] = inc;       // == ecnt
    cnt[t] = 0;                        // reuse as rank counter
  }
  __syncthreads();
#pragma unroll
  for (int u = 0; u < BCAP / 512; ++u) {
    const int e = u * 512 + t;
    if (e < ecnt) {
      const int rl = myv[u].x >> 16;
      const int pos = excl[rl] + atomicAdd(&cnt[rl], 1);
      eL[pos] = make_int2(myv[u].x & 0xffff, myv[u].y);
    }
  }
  __syncthreads();

  const int w = t >> 6;
  const int lane = t & 63;
  const int half = lane >> 5;
  const int la = lane & 31;
  const uint2* xh2 = (const uint2*)xh;

  for (int pp = 0; pp < 4; ++pp) {          // 4 pairs per wave (8 waves)
    const int rl0 = (pp * 8 + w) * 2;       // local row of first node in pair
    const int i = node0 + rl0 + half;
    const int o0 = excl[rl0];
    const int o1 = excl[rl0 + 1];
    const int o2 = excl[rl0 + 2];
    const int d0 = o1 - o0, d1 = o2 - o1;
    const int myoff = half ? o1 : o0;
    const int myd = half ? d1 : d0;
    const int dmax = max(d0, d1);           // wave-uniform
    s_ar[w][half][la] = (i < n) ? a_row[(size_t)i * DA + la] : 0.f;

    float aa0 = 0.f, aa1 = 0.f, aa2 = 0.f, aa3 = 0.f;
    float ap0 = 0.f, ap1 = 0.f, ap2 = 0.f, ap3 = 0.f;
    float deg = 0.f;

    for (int base = 0; base < dmax; base += 32) {
      const int m = myd - base;             // active count for this half
      if (la < m) {
        const int2 e = eL[myoff + base + la];
        spk[w][half][la] = e;
        const uint4* ac = (const uint4*)(a_colh + (size_t)e.x * DA);
        const float* ar = s_ar[w][half];
        float dot = 0.f;
#pragma unroll
        for (int k = 0; k < 4; ++k) {
          const uint4 q = ac[k];
          const float* a = ar + k * 8;
          dot += __uint_as_float(q.x << 16) * a[0] +
                 __uint_as_float(q.x & 0xffff0000u) * a[1] +
                 __uint_as_float(q.y << 16) * a[2] +
                 __uint_as_float(q.y & 0xffff0000u) * a[3] +
                 __uint_as_float(q.z << 16) * a[4] +
                 __uint_as_float(q.z & 0xffff0000u) * a[5] +
                 __uint_as_float(q.w << 16) * a[6] +
                 __uint_as_float(q.w & 0xffff0000u) * a[7];
        }
        const float lg = (dot >= 0.f) ? dot : SLOPE * dot;
        sp[w][half][la] = __expf(lg);       // same-wave RAW, no barrier
      } else {
        spk[w][half][la] = make_int2(0, 0); // col 0, adj 0 -> harmless
        sp[w][half][la] = 0.f;
      }
      const int mmax = min(32, dmax - base);
      int j = 0;
      for (; j + 8 <= mmax; j += 8) {
#pragma unroll
        for (int u = 0; u < 8; ++u) NODE_BODY(j + u)
      }
      for (; j < mmax; ++j) NODE_BODY(j)
    }
    if (i < n) {
      const float inv = 0.5f / (deg + 1e-15f);
      ushort4 h;
      h.x = f2bf(0.5f * aa0 + inv * ap0);
      h.y = f2bf(0.5f * aa1 + inv * ap1);
      h.z = f2bf(0.5f * aa2 + inv * ap2);
      h.w = f2bf(0.5f * aa3 + inv * ap3);
      *(ushort4*)(feath + (size_t)i * DIN + la * 4) = h;
    }
  }
}

// ---------------- K4: MFMA GEMM out = feath @ Wxt^T + b ----------------
__global__ __launch_bounds__(256) void gemm_kernel(
    const ushort* __restrict__ feath, const ushort* __restrict__ wxt,
    const float* __restrict__ bx, float* __restrict__ out) {
  const int t = threadIdx.x;
  const int w = t >> 6;
  const int l = t & 63;
  const int row0 = blockIdx.x * 16;
  const int lr = l & 15;
  const int lk = (l >> 4) * 8;
  const int col0 = w * 64;

  f32x4 acc[4] = {f32x4{0.f, 0.f, 0.f, 0.f}, f32x4{0.f, 0.f, 0.f, 0.f},
                  f32x4{0.f, 0.f, 0.f, 0.f}, f32x4{0.f, 0.f, 0.f, 0.f}};
  const ushort* Abase = feath + (size_t)(row0 + lr) * DIN + lk;
#pragma unroll
  for (int kk = 0; kk < 4; ++kk) {
    const bf16x8 a = *(const bf16x8*)(Abase + kk * 32);
#pragma unroll
    for (int ct = 0; ct < 4; ++ct) {
      const bf16x8 b =
          *(const bf16x8*)(wxt + (size_t)(col0 + ct * 16 + lr) * DIN + kk * 32 + lk);
      acc[ct] = __builtin_amdgcn_mfma_f32_16x16x32_bf16(a, b, acc[ct], 0, 0, 0);
    }
  }
  const int crow0 = row0 + (l >> 4) * 4;
#pragma unroll
  for (int ct = 0; ct < 4; ++ct) {
    const int c = col0 + ct * 16 + lr;
    const float bv = bx[c];
#pragma unroll
    for (int r = 0; r < 4; ++r)
      out[(size_t)(crow0 + r) * DOUT + c] = acc[ct][r] + bv;
  }
}

extern "C" void kernel_launch(void* const* d_in, const int* in_sizes, int n_in,
                              void* d_out, int out_size, void* d_ws, size_t ws_size,
                              hipStream_t stream) {
  const float* x   = (const float*)d_in[0];
  const int*   row = (const int*)d_in[1];
  const int*   col = (const int*)d_in[2];
  const float* adj = (const float*)d_in[3];
  const float* Wr  = (const float*)d_in[4];
  const float* Wc  = (const float*)d_in[5];
  const float* Wx  = (const float*)d_in[6];
  const float* bx  = (const float*)d_in[7];
  float* out = (float*)d_out;

  const int n = in_sizes[0] / DIN;   // 50000
  const int E = in_sizes[1];         // 1600000
  const int nb = (n + 63) >> BSH;    // 782 buckets

  // Workspace layout (no overlays: ibuf lifetime overlaps feath's writers)
  int* w4 = (int*)d_ws;
  float* a_row   = (float*)w4;  w4 += (size_t)n * DA;          // 6.4 MB
  ushort* feath  = (ushort*)w4; w4 += (size_t)n * DIN / 2;     // 12.8 MB
  ushort* a_colh = (ushort*)w4; w4 += (size_t)n * DA / 2;      // 3.2 MB
  uint*   xh     = (uint*)w4;   w4 += (size_t)n * DIN / 2;     // 12.8 MB
  int2*   ibuf   = (int2*)w4;   w4 += (size_t)nb * BCAP * 2;   // 16.0 MB
  int*    bcursor= w4;          w4 += (size_t)nb * CSTRIDE;    // 0.1 MB
  ushort* wxt    = (ushort*)w4; w4 += (size_t)DOUT * DIN / 2;  // 64 KB
  ushort* wrct   = (ushort*)w4;                                // 16 KB
  // total ~= 51.4 MB

  wconv_kernel<<<21, 256, 0, stream>>>(Wx, wxt, Wr, Wc, wrct, bcursor, nb);
  proj_kernel<<<n / 16, 256, 0, stream>>>(x, wrct, a_row, a_colh, (ushort*)xh);
  part_kernel<<<(E + PB_CHUNK - 1) / PB_CHUNK, 512, 0, stream>>>(
      row, col, adj, bcursor, ibuf, nb, E);
  node_kernel<<<nb, 512, 0, stream>>>(
      (const uint*)xh, a_row, a_colh, bcursor, ibuf, feath, n);
  gemm_kernel<<<n / 16, 256, 0, stream>>>(feath, wxt, bx, out);
}